// Round 8
// baseline (750046.729 us; speedup 1.0000x reference)
//
#include <hip/hip_runtime.h>
#include <math.h>

#define DIM   256
#define LDM   260
#define NT    1024
#define TSTEPS 512
#define CLIPV 1.0e6f
#define TJIT  1.0e-4f
#define CJIT  1.0e-5f
#define MAXNLL 1.0e4f
#define LOG2PI 1.8378770664093453f

#define MAT 66560
// buffers: 0=P 1=APT 2=SY 3=PP 4=S 5=L 6=G 7=Q 8=R
__device__ __align__(16) float g_ws[9 * MAT];

__device__ __forceinline__ float fsan(float x) {
    x = isnan(x) ? 0.0f : x;
    return fminf(fmaxf(x, -CLIPV), CLIPV);
}
__device__ __forceinline__ float rdlane(float v, int l) {
    return __int_as_float(__builtin_amdgcn_readlane(__float_as_int(v), l));
}
__device__ __forceinline__ float wave_sum(float v) {
    #pragma unroll
    for (int off = 32; off; off >>= 1) v += __shfl_xor(v, off, 64);
    return v;
}

// one-wave 64x64 Cholesky reading ONLY the lower triangle of src (stride sstride).
__attribute__((noinline))
__device__ void chol64(const float* src, int sstride, float* Lm, float* rdiag, int b0) {
    const int lane = threadIdx.x & 63;
    float a[64];
    const float* srow = src + (size_t)lane * sstride;
    #pragma unroll
    for (int k = 0; k < 64; k += 4) {
        float4 v = *(const float4*)(srow + k);
        a[k] = v.x; a[k+1] = v.y; a[k+2] = v.z; a[k+3] = v.w;
    }
    float rdv = 0.0f;
    #pragma unroll
    for (int j = 0; j < 64; ++j) {
        float d  = rdlane(a[j], j);
        float rs = 1.0f / sqrtf(d);
        if (lane == j) rdv = rs;
        if (lane >= j) a[j] *= rs;          // a[j] = l_ij for rows i >= j
        #pragma unroll
        for (int k = j + 1; k < 64; ++k) {
            float lkj = rdlane(a[j], k);    // l_kj (lower, already scaled)
            if (lane > j) a[k] = fmaf(-a[j], lkj, a[k]);
        }
    }
    float* lrow = Lm + (size_t)(b0 + lane) * LDM + b0;
    #pragma unroll
    for (int k = 0; k < 64; k += 4) {
        float4 v; v.x = a[k]; v.y = a[k+1]; v.z = a[k+2]; v.w = a[k+3];
        *(float4*)(lrow + k) = v;
    }
    rdiag[b0 + lane] = rdv;
}

// one wave solves L[b0 diag] x = Sm[c, b0:b0+64], writes L[c, b0:b0+64].
__device__ void trsm_col_wave(const float* Sm, float* Lm, const float* rdiag, int b0, int c) {
    const int lane = threadIdx.x & 63;
    float b   = Sm[(size_t)c * LDM + b0 + lane];
    float rdl = rdiag[b0 + lane];
    float x   = 0.0f;
    const float* lbase = Lm + (size_t)(b0 + lane) * LDM + b0;
    for (int i0 = 0; i0 < 64; i0 += 4) {
        float4 lv = *(const float4*)(lbase + i0);
        #pragma unroll
        for (int s = 0; s < 4; ++s) {
            int i = i0 + s;
            float xi = rdlane(b, i) * rdlane(rdl, i);
            x = (lane == i) ? xi : x;
            float lvi = (s == 0) ? lv.x : (s == 1) ? lv.y : (s == 2) ? lv.z : lv.w;
            b = fmaf(-lvi, xi, b);   // lanes <= i corrupt their own dead b harmlessly
        }
    }
    Lm[(size_t)c * LDM + b0 + lane] = x;
}

// one wave: two forward solves L y = PP[:,ca], PP[:,cb]; scatter into G[k][c] (k-major).
__device__ void gsolve2(const float* PPm, const float* Lm, const float* rd,
                        float* Gm, int ca, int cb) {
    const int lane = threadIdx.x & 63;
    float b1[4], b2[4], x1[4], x2[4], rdv[4];
    const float* lp[4];
    #pragma unroll
    for (int q = 0; q < 4; ++q) {
        int r = lane + 64 * q;
        b1[q] = PPm[(size_t)ca * LDM + r];
        b2[q] = PPm[(size_t)cb * LDM + r];
        x1[q] = 0.0f; x2[q] = 0.0f;
        rdv[q] = rd[r];
        lp[q] = Lm + (size_t)r * LDM;
    }
    #pragma unroll
    for (int q = 0; q < 4; ++q) {
        for (int ii0 = 0; ii0 < 64; ii0 += 4) {
            float4 a0 = *(const float4*)(lp[0] + q * 64 + ii0);
            float4 a1 = *(const float4*)(lp[1] + q * 64 + ii0);
            float4 a2 = *(const float4*)(lp[2] + q * 64 + ii0);
            float4 a3 = *(const float4*)(lp[3] + q * 64 + ii0);
            #pragma unroll
            for (int s = 0; s < 4; ++s) {
                int il = ii0 + s;
                float rr  = rdlane(rdv[q], il);
                float xi1 = rdlane(b1[q], il) * rr;
                float xi2 = rdlane(b2[q], il) * rr;
                x1[q] = (lane == il) ? xi1 : x1[q];
                x2[q] = (lane == il) ? xi2 : x2[q];
                float c0 = (s==0)?a0.x:(s==1)?a0.y:(s==2)?a0.z:a0.w;
                float c1 = (s==0)?a1.x:(s==1)?a1.y:(s==2)?a1.z:a1.w;
                float c2 = (s==0)?a2.x:(s==1)?a2.y:(s==2)?a2.z:a2.w;
                float c3 = (s==0)?a3.x:(s==1)?a3.y:(s==2)?a3.z:a3.w;
                b1[0] = fmaf(-c0, xi1, b1[0]);  b2[0] = fmaf(-c0, xi2, b2[0]);
                b1[1] = fmaf(-c1, xi1, b1[1]);  b2[1] = fmaf(-c1, xi2, b2[1]);
                b1[2] = fmaf(-c2, xi1, b1[2]);  b2[2] = fmaf(-c2, xi2, b2[2]);
                b1[3] = fmaf(-c3, xi1, b1[3]);  b2[3] = fmaf(-c3, xi2, b2[3]);
            }
        }
    }
    #pragma unroll
    for (int q = 0; q < 4; ++q) {
        int r = lane + 64 * q;
        Gm[(size_t)r * LDM + ca] = x1[q];
        Gm[(size_t)r * LDM + cb] = x2[q];
    }
}

// one wave: forward solve L z = innov (LDS), write zvec (LDS).
__device__ void gsolve_z(const float* Lm, const float* rd, const float* innov, float* zv) {
    const int lane = threadIdx.x & 63;
    float b[4], x[4], rdv[4];
    const float* lp[4];
    #pragma unroll
    for (int q = 0; q < 4; ++q) {
        int r = lane + 64 * q;
        b[q] = innov[r]; x[q] = 0.0f; rdv[q] = rd[r];
        lp[q] = Lm + (size_t)r * LDM;
    }
    #pragma unroll
    for (int q = 0; q < 4; ++q) {
        for (int ii0 = 0; ii0 < 64; ii0 += 4) {
            float4 a0 = *(const float4*)(lp[0] + q * 64 + ii0);
            float4 a1 = *(const float4*)(lp[1] + q * 64 + ii0);
            float4 a2 = *(const float4*)(lp[2] + q * 64 + ii0);
            float4 a3 = *(const float4*)(lp[3] + q * 64 + ii0);
            #pragma unroll
            for (int s = 0; s < 4; ++s) {
                int il = ii0 + s;
                float xi = rdlane(b[q], il) * rdlane(rdv[q], il);
                x[q] = (lane == il) ? xi : x[q];
                float c0 = (s==0)?a0.x:(s==1)?a0.y:(s==2)?a0.z:a0.w;
                float c1 = (s==0)?a1.x:(s==1)?a1.y:(s==2)?a1.z:a1.w;
                float c2 = (s==0)?a2.x:(s==1)?a2.y:(s==2)?a2.z:a2.w;
                float c3 = (s==0)?a3.x:(s==1)?a3.y:(s==2)?a3.z:a3.w;
                b[0] = fmaf(-c0, xi, b[0]);
                b[1] = fmaf(-c1, xi, b[1]);
                b[2] = fmaf(-c2, xi, b[2]);
                b[3] = fmaf(-c3, xi, b[3]);
            }
        }
    }
    #pragma unroll
    for (int q = 0; q < 4; ++q) zv[lane + 64 * q] = x[q];
}

// one-wave 32x32 trailing tile: Sm[i0..,j0..] -= Lp(i0)*Lp(j0)^T (k=64 at col b0)
__device__ void trail_tile_wave(float* Sm, const float* Lm, int i0, int j0, int b0) {
    const int lane = threadIdx.x & 63;
    const int ly = lane >> 3, lx = lane & 7;
    float acc[4][4] = {};
    for (int kk = 0; kk < 64; kk += 4) {
        float4 xv[4], yv[4];
        #pragma unroll
        for (int r = 0; r < 4; ++r)
            xv[r] = *(const float4*)(Lm + (size_t)(i0 + 4*ly + r) * LDM + b0 + kk);
        #pragma unroll
        for (int c = 0; c < 4; ++c)
            yv[c] = *(const float4*)(Lm + (size_t)(j0 + 4*lx + c) * LDM + b0 + kk);
        #pragma unroll
        for (int r = 0; r < 4; ++r)
            #pragma unroll
            for (int c = 0; c < 4; ++c) {
                acc[r][c] = fmaf(xv[r].x, yv[c].x, acc[r][c]);
                acc[r][c] = fmaf(xv[r].y, yv[c].y, acc[r][c]);
                acc[r][c] = fmaf(xv[r].z, yv[c].z, acc[r][c]);
                acc[r][c] = fmaf(xv[r].w, yv[c].w, acc[r][c]);
            }
    }
    #pragma unroll
    for (int r = 0; r < 4; ++r)
        #pragma unroll
        for (int c = 0; c < 4; ++c)
            Sm[(size_t)(i0 + 4*ly + r) * LDM + j0 + 4*lx + c] -= acc[r][c];
}

// lower 32-tiles of trailing region [rb, rb+32*nt)^2 spread over 16 waves
__device__ void trail_region(float* Sm, const float* Lm, int rb, int nt, int b0, int wv) {
    const int cnt = nt * (nt + 1) / 2;
    for (int idx = wv; idx < cnt; idx += 16) {
        int ti = 0, tj = 0;
        for (int a = 0, s = 0; a < nt; ++a) {
            if (idx < s + a + 1) { ti = a; tj = idx - s; break; }
            s += a + 1;
        }
        trail_tile_wave(Sm, Lm, rb + 32 * ti, rb + 32 * tj, b0);
    }
}

__global__ __launch_bounds__(NT, 1) void kf_kernel(
    const float* __restrict__ obs, const float* __restrict__ trans,
    const float* __restrict__ forc, const float* __restrict__ proc,
    const float* __restrict__ meas, const float* __restrict__ im,
    const float* __restrict__ icd, float* __restrict__ out)
{
    __shared__ float ast[32 * 260];        // transposed-operand staging chunk
    __shared__ float mvec[DIM], predm[DIM], innov[DIM], gtzs[DIM], rdiagS[DIM], zvec[DIM];
    __shared__ float scal[2];              // [0]=zz, [1]=logdet

    const int tid  = threadIdx.x;
    const int lane = tid & 63;
    const int wv   = tid >> 6;             // 0..15

    float* Pm  = g_ws + 0 * MAT;
    float* APT = g_ws + 1 * MAT;
    float* SY  = g_ws + 2 * MAT;
    float* PPm = g_ws + 3 * MAT;
    float* Sm  = g_ws + 4 * MAT;
    float* Lm  = g_ws + 5 * MAT;
    float* Gm  = g_ws + 6 * MAT;
    float* Qm  = g_ws + 7 * MAT;
    float* Rm  = g_ws + 8 * MAT;

    float* out_filt = out + 1;
    float* out_pred = out + 1 + (size_t)TSTEPS * DIM;

    // wave tile coords for the 64x64-per-wave GEMM partition
    const int wr = wv >> 2, wc = wv & 3;
    const int r0 = wr * 64 + (lane >> 3) * 8;
    const int c0 = wc * 64 + (lane & 7) * 8;

    // ---------------- init ----------------
    for (int e = tid; e < DIM * DIM; e += NT) {
        int i = e >> 8, j = e & 255;
        Qm[(size_t)i * LDM + j] = 0.5f * (fsan(proc[i * 256 + j]) + fsan(proc[j * 256 + i]))
                                  + (i == j ? TJIT : 0.0f);
        Rm[(size_t)i * LDM + j] = 0.5f * (fsan(meas[i * 256 + j]) + fsan(meas[j * 256 + i]));
        Pm[(size_t)i * LDM + j] = (i == j) ? fminf(fmaxf(icd[i], 1e-6f), CLIPV) : 0.0f;
    }
    if (tid < 256) mvec[tid] = fsan(im[tid]);
    __syncthreads();

    float nllsum = 0.0f;   // thread 0's copy is authoritative

    for (int t = 0; t < TSTEPS; ++t) {
        const float* At = trans + (size_t)t * DIM * DIM;

        // ---- (a) pred_m = san(A)@m + f ; innov ----
        for (int rr = 0; rr < 16; ++rr) {
            int r = wv * 16 + rr;
            float s = 0.0f;
            #pragma unroll
            for (int q = 0; q < 4; ++q)
                s = fmaf(fsan(At[(size_t)r * 256 + lane + 64 * q]), mvec[lane + 64 * q], s);
            s = wave_sum(s);
            if (lane == 0) {
                float pm = s + fsan(forc[(size_t)t * DIM + r]);
                predm[r] = pm;
                innov[r] = obs[(size_t)t * DIM + r] - pm;
                out_pred[(size_t)t * DIM + r] = pm;
            }
        }
        __syncthreads();

        // ---- (b) APT = (san(A) @ P)^T : stage A^T chunk in LDS, stream P rows ----
        {
            float acc[8][8] = {};
            for (int kc = 0; kc < 256; kc += 32) {
                #pragma unroll
                for (int it = 0; it < 8; ++it) {
                    int r = (tid >> 5) + 32 * it;
                    int k = tid & 31;
                    ast[k * 260 + r] = fsan(At[(size_t)r * 256 + kc + k]);
                }
                __syncthreads();
                #pragma unroll 2
                for (int kk = 0; kk < 32; ++kk) {
                    float4 a0 = *(const float4*)(ast + kk * 260 + r0);
                    float4 a1 = *(const float4*)(ast + kk * 260 + r0 + 4);
                    const float* prow = Pm + (size_t)(kc + kk) * LDM + c0;
                    float4 b0 = *(const float4*)(prow);
                    float4 b1 = *(const float4*)(prow + 4);
                    float av[8], bv[8];
                    av[0]=a0.x; av[1]=a0.y; av[2]=a0.z; av[3]=a0.w;
                    av[4]=a1.x; av[5]=a1.y; av[6]=a1.z; av[7]=a1.w;
                    bv[0]=b0.x; bv[1]=b0.y; bv[2]=b0.z; bv[3]=b0.w;
                    bv[4]=b1.x; bv[5]=b1.y; bv[6]=b1.z; bv[7]=b1.w;
                    #pragma unroll
                    for (int r = 0; r < 8; ++r)
                        #pragma unroll
                        for (int c = 0; c < 8; ++c)
                            acc[r][c] = fmaf(av[r], bv[c], acc[r][c]);
                }
                __syncthreads();
            }
            #pragma unroll
            for (int c = 0; c < 8; ++c) {
                float4 v0; v0.x=acc[0][c]; v0.y=acc[1][c]; v0.z=acc[2][c]; v0.w=acc[3][c];
                float4 v1; v1.x=acc[4][c]; v1.y=acc[5][c]; v1.z=acc[6][c]; v1.w=acc[7][c];
                *(float4*)(APT + (size_t)(c0 + c) * LDM + r0)     = v0;
                *(float4*)(APT + (size_t)(c0 + c) * LDM + r0 + 4) = v1;
            }
        }
        __syncthreads();

        // ---- (c) SY = AP @ san(A)^T : stage A^T chunk in LDS, stream APT rows ----
        {
            float acc[8][8] = {};
            for (int kc = 0; kc < 256; kc += 32) {
                #pragma unroll
                for (int it = 0; it < 8; ++it) {
                    int r = (tid >> 5) + 32 * it;    // r plays the j role here
                    int k = tid & 31;
                    ast[k * 260 + r] = fsan(At[(size_t)r * 256 + kc + k]);
                }
                __syncthreads();
                #pragma unroll 2
                for (int kk = 0; kk < 32; ++kk) {
                    const float* arow = APT + (size_t)(kc + kk) * LDM + r0;
                    float4 a0 = *(const float4*)(arow);
                    float4 a1 = *(const float4*)(arow + 4);
                    float4 b0 = *(const float4*)(ast + kk * 260 + c0);
                    float4 b1 = *(const float4*)(ast + kk * 260 + c0 + 4);
                    float av[8], bv[8];
                    av[0]=a0.x; av[1]=a0.y; av[2]=a0.z; av[3]=a0.w;
                    av[4]=a1.x; av[5]=a1.y; av[6]=a1.z; av[7]=a1.w;
                    bv[0]=b0.x; bv[1]=b0.y; bv[2]=b0.z; bv[3]=b0.w;
                    bv[4]=b1.x; bv[5]=b1.y; bv[6]=b1.z; bv[7]=b1.w;
                    #pragma unroll
                    for (int r = 0; r < 8; ++r)
                        #pragma unroll
                        for (int c = 0; c < 8; ++c)
                            acc[r][c] = fmaf(av[r], bv[c], acc[r][c]);
                }
                __syncthreads();
            }
            #pragma unroll
            for (int r = 0; r < 8; ++r) {
                float4 v0; v0.x=acc[r][0]; v0.y=acc[r][1]; v0.z=acc[r][2]; v0.w=acc[r][3];
                float4 v1; v1.x=acc[r][4]; v1.y=acc[r][5]; v1.z=acc[r][6]; v1.w=acc[r][7];
                *(float4*)(SY + (size_t)(r0 + r) * LDM + c0)     = v0;
                *(float4*)(SY + (size_t)(r0 + r) * LDM + c0 + 4) = v1;
            }
        }
        __syncthreads();

        // ---- (d) PP = sym(SY)+Q (full), S = PP+R+cI (lower) ----
        for (int e = tid; e < DIM * DIM; e += NT) {
            int i = e >> 8, j = e & 255;
            if (i >= j) {
                float sym = 0.5f * (SY[(size_t)i * LDM + j] + SY[(size_t)j * LDM + i]);
                float pp  = sym + Qm[(size_t)i * LDM + j];
                PPm[(size_t)i * LDM + j] = pp;
                PPm[(size_t)j * LDM + i] = pp;
                Sm[(size_t)i * LDM + j]  = pp + Rm[(size_t)i * LDM + j] + (i == j ? CJIT : 0.0f);
            }
        }
        __syncthreads();

        // ---- (e) blocked Cholesky: wave0 chol64s, trsm/trail over 16 waves ----
        if (wv == 0) chol64(Sm, LDM, Lm, rdiagS, 0);
        __syncthreads();
        for (int i = 0; i < 12; ++i) trsm_col_wave(Sm, Lm, rdiagS, 0, 64 + wv + 16 * i);
        __syncthreads();
        trail_region(Sm, Lm, 64, 6, 0, wv);
        __syncthreads();
        if (wv == 0) chol64(Sm + (size_t)64 * LDM + 64, LDM, Lm, rdiagS, 64);
        __syncthreads();
        for (int i = 0; i < 8; ++i) trsm_col_wave(Sm, Lm, rdiagS, 64, 128 + wv + 16 * i);
        __syncthreads();
        trail_region(Sm, Lm, 128, 4, 64, wv);
        __syncthreads();
        if (wv == 0) chol64(Sm + (size_t)128 * LDM + 128, LDM, Lm, rdiagS, 128);
        __syncthreads();
        for (int i = 0; i < 4; ++i) trsm_col_wave(Sm, Lm, rdiagS, 128, 192 + wv + 16 * i);
        __syncthreads();
        trail_region(Sm, Lm, 192, 2, 128, wv);
        __syncthreads();
        if (wv == 0) chol64(Sm + (size_t)192 * LDM + 192, LDM, Lm, rdiagS, 192);
        __syncthreads();

        // ---- (f) G = L^{-1} PP (k-major scatter), z = L^{-1} innov ----
        for (int rr = 0; rr < 8; ++rr)
            gsolve2(PPm, Lm, rdiagS, Gm, wv + 32 * rr, wv + 32 * rr + 16);
        if (wv == 0) gsolve_z(Lm, rdiagS, innov, zvec);
        __syncthreads();

        // ---- (g) newP = PP - G^T G (streamed, fused subtract) ----
        {
            float acc[8][8] = {};
            #pragma unroll 2
            for (int kk = 0; kk < 256; ++kk) {
                const float* grow = Gm + (size_t)kk * LDM;
                float4 a0 = *(const float4*)(grow + r0);
                float4 a1 = *(const float4*)(grow + r0 + 4);
                float4 b0 = *(const float4*)(grow + c0);
                float4 b1 = *(const float4*)(grow + c0 + 4);
                float av[8], bv[8];
                av[0]=a0.x; av[1]=a0.y; av[2]=a0.z; av[3]=a0.w;
                av[4]=a1.x; av[5]=a1.y; av[6]=a1.z; av[7]=a1.w;
                bv[0]=b0.x; bv[1]=b0.y; bv[2]=b0.z; bv[3]=b0.w;
                bv[4]=b1.x; bv[5]=b1.y; bv[6]=b1.z; bv[7]=b1.w;
                #pragma unroll
                for (int r = 0; r < 8; ++r)
                    #pragma unroll
                    for (int c = 0; c < 8; ++c)
                        acc[r][c] = fmaf(av[r], bv[c], acc[r][c]);
            }
            #pragma unroll
            for (int r = 0; r < 8; ++r) {
                const float* pprow = PPm + (size_t)(r0 + r) * LDM + c0;
                float4 p0 = *(const float4*)(pprow);
                float4 p1 = *(const float4*)(pprow + 4);
                float4 v0; v0.x=p0.x-acc[r][0]; v0.y=p0.y-acc[r][1]; v0.z=p0.z-acc[r][2]; v0.w=p0.w-acc[r][3];
                float4 v1; v1.x=p1.x-acc[r][4]; v1.y=p1.y-acc[r][5]; v1.z=p1.z-acc[r][6]; v1.w=p1.w-acc[r][7];
                *(float4*)(Pm + (size_t)(r0 + r) * LDM + c0)     = v0;
                *(float4*)(Pm + (size_t)(r0 + r) * LDM + c0 + 4) = v1;
            }
        }
        __syncthreads();

        // ---- (h1) gtz = G^T z ; zz ; logdet ----
        if (tid < 256) {
            float s0 = 0, s1 = 0, s2 = 0, s3 = 0;
            for (int k = 0; k < 256; k += 4) {
                s0 = fmaf(Gm[(size_t)(k    ) * LDM + tid], zvec[k    ], s0);
                s1 = fmaf(Gm[(size_t)(k + 1) * LDM + tid], zvec[k + 1], s1);
                s2 = fmaf(Gm[(size_t)(k + 2) * LDM + tid], zvec[k + 2], s2);
                s3 = fmaf(Gm[(size_t)(k + 3) * LDM + tid], zvec[k + 3], s3);
            }
            gtzs[tid] = (s0 + s1) + (s2 + s3);
        } else if (wv == 4) {
            float s = 0.0f;
            #pragma unroll
            for (int q = 0; q < 4; ++q) { float z = zvec[lane + 64 * q]; s = fmaf(z, z, s); }
            s = wave_sum(s);
            if (lane == 0) scal[0] = s;
        } else if (wv == 5) {
            float s = 0.0f;
            #pragma unroll
            for (int q = 0; q < 4; ++q) s += logf(rdiagS[lane + 64 * q]);
            s = wave_sum(s);
            if (lane == 0) scal[1] = -2.0f * s;   // logdet = 2*sum(log L_ii)
        }
        __syncthreads();

        // ---- (h2) finalize: new_m, out_filt, nll ----
        if (tid < 256) {
            float nm = predm[tid] + gtzs[tid];
            mvec[tid] = nm;
            out_filt[(size_t)t * DIM + tid] = nm;
        }
        if (tid == 0) {
            float nll = 0.5f * (scal[0] + scal[1] + 256.0f * LOG2PI);
            nllsum += fminf(nll, MAXNLL);
        }
        __syncthreads();
    }

    if (tid == 0) out[0] = nllsum;
}

extern "C" void kernel_launch(void* const* d_in, const int* in_sizes, int n_in,
                              void* d_out, int out_size, void* d_ws, size_t ws_size,
                              hipStream_t stream) {
    (void)in_sizes; (void)n_in; (void)out_size; (void)d_ws; (void)ws_size;
    const float* obs  = (const float*)d_in[0];
    const float* trn  = (const float*)d_in[1];
    const float* forc = (const float*)d_in[2];
    const float* proc = (const float*)d_in[3];
    const float* meas = (const float*)d_in[4];
    const float* im   = (const float*)d_in[5];
    const float* icd  = (const float*)d_in[6];
    float* out = (float*)d_out;

    kf_kernel<<<dim3(1), dim3(NT), 0, stream>>>(obs, trn, forc, proc, meas, im, icd, out);
}